// Round 11
// baseline (38.078 us; speedup 1.0000x reference)
//
#include <hip/hip_runtime.h>
#include <hip/hip_fp16.h>
#include <math.h>

constexpr int F    = 128;
constexpr int KN   = 48;
constexpr int NG   = 25;
constexpr int TN   = 176;         // table intervals; 177 nodes, h = 5/176
constexpr int MAXZ = 100;

typedef _Float16 f16x8 __attribute__((ext_vector_type(8)));
typedef float    f32x4 __attribute__((ext_vector_type(4)));

__device__ __forceinline__ float ssp(float x) {
    // softplus(x) - ln2 = max(x,0) + log(0.5*exp(-|x|) + 0.5)
    return fmaxf(x, 0.0f) + __logf(fmaf(0.5f, __expf(-fabsf(x)), 0.5f));
}

__device__ __forceinline__ unsigned short f2h(float x) {
    return __half_as_ushort(__float2half_rn(x));
}
__device__ __forceinline__ __half2 u2h2(unsigned int u) {
    union { unsigned int u; __half2 h; } c; c.u = u; return c.h;
}

// ============ prep: table rows | o-weight frags | embed projection ===========
// grid = (TN+1) + 128 + (MAXZ+1)
__global__ __launch_bounds__(256) void k_prep(
    const float* __restrict__ f1w, const float* __restrict__ f1b,
    const float* __restrict__ f2w, const float* __restrict__ f2b,
    const float* __restrict__ o1w, const float* __restrict__ o2w,
    const float* __restrict__ embed, const float* __restrict__ in2f,
    unsigned int* __restrict__ tabp, unsigned int* __restrict__ yzp,
    unsigned short* __restrict__ o1f, unsigned short* __restrict__ o2f, int N)
{
    __shared__ float s0[F];
    __shared__ float s1[F];
    int bid = blockIdx.x;
    int tid = threadIdx.x;

    if (bid < TN + 1) {
        // ---- table row j, linear f16 (packed as adjacent-feature u32) ----
        int j = bid, f = tid;
        float d = (float)j * (5.0f / (float)TN);
        constexpr float width = 5.0f / 24.0f;
        constexpr float coeff = -0.5f / (width * width);
        if (f < F) {
            float z = f1b[f];
            #pragma unroll
            for (int c = 0; c < NG; ++c) {
                float t = d - (float)c * width;
                z = fmaf(__expf(coeff * t * t), f1w[c * F + f], z);
            }
            s0[f] = ssp(z);
        }
        __syncthreads();
        if (f < F) {
            float w = f2b[f];
            #pragma unroll 8
            for (int c = 0; c < F; ++c)
                w = fmaf(s0[c], f2w[c * F + f], w);
            float cut = 0.5f * (cosf(d * 0.62831853071795864769f) + 1.0f);
            cut = (d < 5.0f) ? cut : 0.0f;
            s1[f] = w * cut;
        }
        __syncthreads();
        if (f < 64)
            tabp[j * 64 + f] = (unsigned int)f2h(s1[2 * f]) | ((unsigned int)f2h(s1[2 * f + 1]) << 16);
        return;
    }
    bid -= TN + 1;

    if (bid < 128) {
        // ---- o1w/o2w -> MFMA B-frag-major f16 ----
        int t = bid * 256 + tid;            // 0..32767
        int e = t & 16383;
        int j = e & 7, l = (e >> 3) & 63, nt = (e >> 9) & 7, kt = e >> 12;
        int k = kt * 32 + ((l >> 4) << 3) + j;
        int col = nt * 16 + (l & 15);
        if (t < 16384) o1f[e] = f2h(o1w[k * F + col]);
        else           o2f[e] = f2h(o2w[k * F + col]);
        return;
    }
    bid -= 128;

    {
        // ---- yzp[z] = linear f16 of embed[z] @ in2f; row MAXZ = 0 ----
        int z = bid, f = tid;
        if (z < MAXZ) {
            if (f < F) s0[f] = embed[z * F + f];
            __syncthreads();
            if (f < F) {
                float acc = 0.f;
                #pragma unroll 8
                for (int c = 0; c < F; ++c)
                    acc = fmaf(s0[c], in2f[c * F + f], acc);
                s1[f] = acc;
            }
        } else {
            if (f < F) s1[f] = 0.f;
            __syncthreads();
        }
        __syncthreads();
        if (f < 64)
            yzp[z * 64 + f] = (unsigned int)f2h(s1[2 * f]) | ((unsigned int)f2h(s1[2 * f + 1]) << 16);
    }
}

// ============ fused main: on-the-fly params + pairagg + output net ===========
// 512 threads (8 waves), persistent. Per 16-atom group:
//   pre:    lanes 0-47 build packed params for the wave's 2 atoms (registers)
//   phase1: HALF-WAVE per pair: lanes 0-31 atom A, 32-63 atom B; each lane owns
//           4 features (b64 table read, rows j / j+1 via offset:256; dwordx2 y)
//   phase2: wave w = col-tile w of out-net (MFMA1 -> ssp -> MFMA2 -> +residual)
// LDS: tabL 45312 B | aggL 4096 B | Us 4096 B = 53504 B -> 3 blocks/CU
__global__ __launch_bounds__(512, 6) void k_main(
    const float* __restrict__ dR, const int* __restrict__ nbr,
    const int* __restrict__ Z,
    const unsigned int* __restrict__ tabp,
    const unsigned int* __restrict__ yzp,
    const unsigned short* __restrict__ o1f, const float* __restrict__ o1b,
    const unsigned short* __restrict__ o2f, const float* __restrict__ o2b,
    const float* __restrict__ embed,
    float* __restrict__ out, int N, int ngroups)
{
    extern __shared__ unsigned int smem[];
    unsigned int*   tabL = smem;                                   // 11328 u32
    unsigned int*   aggL = smem + 11328;                           // 1024 u32
    unsigned short* Us   = (unsigned short*)(smem + 11328 + 1024); // 2048 u16

    int tid  = threadIdx.x;
    int wid  = tid >> 6;
    int lane = tid & 63;
    int lr   = lane & 15;
    int lg   = lane >> 4;
    int h    = lane >> 5;      // half-wave: 0 = atom A, 1 = atom B
    int l5   = lane & 31;

    for (int m = tid; m < (TN + 1) * 64; m += 512)
        tabL[m] = tabp[m];
    __syncthreads();

    for (int g = blockIdx.x; g < ngroups; g += gridDim.x) {
        int n0 = g * 16;

        // ---------- phase 1: pair aggregation, half-wave per atom ----------
        int nA = n0 + wid * 2, nB = nA + 1;
        float ac0 = 0.f, ac1 = 0.f, ac2 = 0.f, ac3 = 0.f;
        if (nA < N) {
            int mB = (nB < N) ? nB : nA;

            // --- on-the-fly params: lane k holds atom's k-th pair ---
            unsigned int pA = 0, pB = 0;
            if (lane < KN) {
                float dA = dR[nA * KN + lane];
                int   iA = nbr[nA * KN + lane];
                float uA = dA * ((float)TN / 5.0f);
                int   jA = (int)uA; jA = (jA > TN - 1) ? (TN - 1) : jA;
                float fA = uA - (float)jA;
                unsigned int zA = (iA >= 0 && iA < N) ? (unsigned int)Z[iA] : (unsigned int)MAXZ;
                pA = ((unsigned int)f2h(fA) << 16) | ((unsigned int)jA << 7) | zA;

                float dB = dR[mB * KN + lane];
                int   iB = nbr[mB * KN + lane];
                float uB = dB * ((float)TN / 5.0f);
                int   jB = (int)uB; jB = (jB > TN - 1) ? (TN - 1) : jB;
                float fB = uB - (float)jB;
                unsigned int zB = (iB >= 0 && iB < N) ? (unsigned int)Z[iB] : (unsigned int)MAXZ;
                pB = ((unsigned int)f2h(fB) << 16) | ((unsigned int)jB << 7) | zB;
            }

            const char* tbase = (const char*)tabL + (l5 << 3);
            const char* ybase = (const char*)yzp + (l5 << 3);

            #pragma unroll
            for (int c = 0; c < 4; ++c) {
                __half2 pac0 = u2h2(0u);
                __half2 pac1 = u2h2(0u);
                #pragma unroll
                for (int k2 = 0; k2 < 12; ++k2) {
                    int k = c * 12 + k2;
                    unsigned int qA = (unsigned int)__builtin_amdgcn_readlane((int)pA, k);
                    unsigned int qB = (unsigned int)__builtin_amdgcn_readlane((int)pB, k);
                    unsigned int q  = h ? qB : qA;

                    __half2 fr2 = u2h2((q & 0xFFFF0000u) | (q >> 16));
                    unsigned int jb = (q & 0x7F80u) << 1;   // j*256 bytes
                    unsigned int zb = (q & 0x7Fu) << 8;     // z*256 bytes

                    const char* tp = tbase + jb;
                    uint2 t0 = *(const uint2*)(tp);         // row j:   features 4l5..4l5+3
                    uint2 t1 = *(const uint2*)(tp + 256);   // row j+1: offset:256
                    uint2 yv = *(const uint2*)(ybase + zb);

                    __half2 w0 = __hfma2(fr2, __hsub2(u2h2(t1.x), u2h2(t0.x)), u2h2(t0.x));
                    __half2 w1 = __hfma2(fr2, __hsub2(u2h2(t1.y), u2h2(t0.y)), u2h2(t0.y));
                    pac0 = __hfma2(w0, u2h2(yv.x), pac0);
                    pac1 = __hfma2(w1, u2h2(yv.y), pac1);
                }
                float2 fa = __half22float2(pac0); ac0 += fa.x; ac1 += fa.y;
                float2 fb = __half22float2(pac1); ac2 += fb.x; ac3 += fb.y;
            }
        }
        // swizzled store: atom a row, feature-words (2l5, 2l5+1) ^ ((a&15)<<2)
        {
            int a    = wid * 2 + h;
            int widx = a * 64 + ((2 * l5) ^ ((a & 15) << 2));
            aggL[widx]     = (unsigned int)f2h(ac0) | ((unsigned int)f2h(ac1) << 16);
            aggL[widx + 1] = (unsigned int)f2h(ac2) | ((unsigned int)f2h(ac3) << 16);
        }
        __syncthreads();                       // bar1: aggL ready

        // ---------- phase 2: output network (f16 MFMA), col-tile = wid ----------
        f32x4 c1 = {0.f, 0.f, 0.f, 0.f};
        #pragma unroll
        for (int kt = 0; kt < 4; ++kt) {
            f16x8 b = *reinterpret_cast<const f16x8*>(o1f + (((kt * 8 + wid) * 64 + lane) << 3));
            const char* ap = (const char*)aggL + lr * 256 + ((kt * 64 + lg * 16) ^ (lr << 4));
            f16x8 a = *reinterpret_cast<const f16x8*>(ap);
            c1 = __builtin_amdgcn_mfma_f32_16x16x32_f16(a, b, c1, 0, 0, 0);
        }
        int fcol = wid * 16 + lr;
        float bv1 = o1b[fcol];
        #pragma unroll
        for (int jr = 0; jr < 4; ++jr) {
            int r = lg * 4 + jr;
            float u = ssp(c1[jr] + bv1);
            Us[r * F + (fcol ^ (r << 3))] = f2h(u);
        }
        __syncthreads();                       // bar2: Us ready

        f32x4 c2 = {0.f, 0.f, 0.f, 0.f};
        #pragma unroll
        for (int kt = 0; kt < 4; ++kt) {
            f16x8 b = *reinterpret_cast<const f16x8*>(o2f + (((kt * 8 + wid) * 64 + lane) << 3));
            f16x8 a = *reinterpret_cast<const f16x8*>(&Us[lr * F + ((kt * 32 + lg * 8) ^ (lr << 3))]);
            c2 = __builtin_amdgcn_mfma_f32_16x16x32_f16(a, b, c2, 0, 0, 0);
        }
        float bv2 = o2b[fcol];
        #pragma unroll
        for (int jr = 0; jr < 4; ++jr) {
            int r = lg * 4 + jr;
            int n = n0 + r;
            if (n < N) {
                float x = embed[Z[n] * F + fcol];
                out[n * F + fcol] = x + c2[jr] + bv2;
            }
        }
    }
}

extern "C" void kernel_launch(void* const* d_in, const int* in_sizes, int n_in,
                              void* d_out, int out_size, void* d_ws, size_t ws_size,
                              hipStream_t stream) {
    const float* dR    = (const float*)d_in[0];
    const int*   Z     = (const int*)  d_in[1];
    const int*   nbr   = (const int*)  d_in[2];
    const float* embed = (const float*)d_in[3];
    const float* in2f  = (const float*)d_in[4];
    const float* f1w   = (const float*)d_in[5];
    const float* f1b   = (const float*)d_in[6];
    const float* f2w   = (const float*)d_in[7];
    const float* f2b   = (const float*)d_in[8];
    const float* o1w   = (const float*)d_in[9];
    const float* o1b   = (const float*)d_in[10];
    const float* o2w   = (const float*)d_in[11];
    const float* o2b   = (const float*)d_in[12];

    int N = in_sizes[1];

    // ws layout (16B-aligned), ~135 KB total
    char* wp = (char*)d_ws;
    unsigned int*   tabp = (unsigned int*)wp;   wp += (size_t)(TN + 1) * 64 * 4;   // 45.3 KB
    unsigned int*   yzp  = (unsigned int*)wp;   wp += (size_t)(MAXZ + 1) * 64 * 4; // 25.9 KB
    unsigned short* o1f  = (unsigned short*)wp; wp += 16384 * 2;                   // 32 KB
    unsigned short* o2f  = (unsigned short*)wp;                                    // 32 KB

    int grid_prep = (TN + 1) + 128 + (MAXZ + 1);

    int ngroups   = (N + 15) / 16;
    int grid_main = (ngroups < 768) ? ngroups : 768;
    int lds_main  = (TN + 1) * 64 * 4 + 4096 + 4096;   // 53504 B -> 3 blocks/CU

    (void)hipFuncSetAttribute((const void*)k_main,
                              hipFuncAttributeMaxDynamicSharedMemorySize, lds_main);

    k_prep<<<grid_prep, 256, 0, stream>>>(f1w, f1b, f2w, f2b, o1w, o2w,
                                          embed, in2f, tabp, yzp, o1f, o2f, N);
    k_main<<<grid_main, 512, lds_main, stream>>>(dR, nbr, Z, tabp, yzp,
                                                 o1f, o1b, o2f, o2b,
                                                 embed, (float*)d_out,
                                                 N, ngroups);
}

// Round 13
// 36.500 us; speedup vs baseline: 1.0432x; 1.0432x over previous
//
#include <hip/hip_runtime.h>
#include <hip/hip_fp16.h>
#include <math.h>

constexpr int F    = 128;
constexpr int KN   = 48;
constexpr int NG   = 25;
constexpr int TN   = 176;         // table intervals; 177 nodes, h = 5/176
constexpr int MAXZ = 100;

typedef _Float16 f16x8 __attribute__((ext_vector_type(8)));
typedef float    f32x4 __attribute__((ext_vector_type(4)));

__device__ __forceinline__ float ssp(float x) {
    // softplus(x) - ln2 = max(x,0) + log(0.5*exp(-|x|) + 0.5)
    return fmaxf(x, 0.0f) + __logf(fmaf(0.5f, __expf(-fabsf(x)), 0.5f));
}

__device__ __forceinline__ unsigned short f2h(float x) {
    return __half_as_ushort(__float2half_rn(x));
}
__device__ __forceinline__ __half2 u2h2(unsigned int u) {
    union { unsigned int u; __half2 h; } c; c.u = u; return c.h;
}

// ============ prep: table rows | o-weight frags | embed projection ===========
// grid = (TN+1) + 128 + (MAXZ+1)
__global__ __launch_bounds__(256) void k_prep(
    const float* __restrict__ f1w, const float* __restrict__ f1b,
    const float* __restrict__ f2w, const float* __restrict__ f2b,
    const float* __restrict__ o1w, const float* __restrict__ o2w,
    const float* __restrict__ embed, const float* __restrict__ in2f,
    unsigned int* __restrict__ tabp, unsigned int* __restrict__ yzp,
    unsigned short* __restrict__ o1f, unsigned short* __restrict__ o2f, int N)
{
    __shared__ float s0[F];
    __shared__ float s1[F];
    int bid = blockIdx.x;
    int tid = threadIdx.x;

    if (bid < TN + 1) {
        // ---- table row j, linear f16 (packed as adjacent-feature u32) ----
        int j = bid, f = tid;
        float d = (float)j * (5.0f / (float)TN);
        constexpr float width = 5.0f / 24.0f;
        constexpr float coeff = -0.5f / (width * width);
        if (f < F) {
            float z = f1b[f];
            #pragma unroll
            for (int c = 0; c < NG; ++c) {
                float t = d - (float)c * width;
                z = fmaf(__expf(coeff * t * t), f1w[c * F + f], z);
            }
            s0[f] = ssp(z);
        }
        __syncthreads();
        if (f < F) {
            float w = f2b[f];
            #pragma unroll 8
            for (int c = 0; c < F; ++c)
                w = fmaf(s0[c], f2w[c * F + f], w);
            float cut = 0.5f * (cosf(d * 0.62831853071795864769f) + 1.0f);
            cut = (d < 5.0f) ? cut : 0.0f;
            s1[f] = w * cut;
        }
        __syncthreads();
        if (f < 64)
            tabp[j * 64 + f] = (unsigned int)f2h(s1[2 * f]) | ((unsigned int)f2h(s1[2 * f + 1]) << 16);
        return;
    }
    bid -= TN + 1;

    if (bid < 128) {
        // ---- o1w/o2w -> MFMA B-frag-major f16 ----
        int t = bid * 256 + tid;            // 0..32767
        int e = t & 16383;
        int j = e & 7, l = (e >> 3) & 63, nt = (e >> 9) & 7, kt = e >> 12;
        int k = kt * 32 + ((l >> 4) << 3) + j;
        int col = nt * 16 + (l & 15);
        if (t < 16384) o1f[e] = f2h(o1w[k * F + col]);
        else           o2f[e] = f2h(o2w[k * F + col]);
        return;
    }
    bid -= 128;

    {
        // ---- yzp[z] = linear f16 of embed[z] @ in2f; row MAXZ = 0 ----
        int z = bid, f = tid;
        if (z < MAXZ) {
            if (f < F) s0[f] = embed[z * F + f];
            __syncthreads();
            if (f < F) {
                float acc = 0.f;
                #pragma unroll 8
                for (int c = 0; c < F; ++c)
                    acc = fmaf(s0[c], in2f[c * F + f], acc);
                s1[f] = acc;
            }
        } else {
            if (f < F) s1[f] = 0.f;
            __syncthreads();
        }
        __syncthreads();
        if (f < 64)
            yzp[z * 64 + f] = (unsigned int)f2h(s1[2 * f]) | ((unsigned int)f2h(s1[2 * f + 1]) << 16);
    }
}

// ============ fused main: on-the-fly params + pairagg + output net ===========
// 512 threads (8 waves), persistent. Per 16-atom group:
//   pre:    lanes 0-47 build packed params for the wave's 2 atoms (registers)
//   phase1: readlane-broadcast params; f16 lerp+weight+accum (4x12 chunks)
//   phase2: wave w = col-tile w of out-net (MFMA1 -> ssp -> MFMA2 -> +residual)
// LDS: tabL 45312 B | aggL 4096 B | Us 4096 B = 53504 B -> 3 blocks/CU
__global__ __launch_bounds__(512, 6) void k_main(
    const float* __restrict__ dR, const int* __restrict__ nbr,
    const int* __restrict__ Z,
    const unsigned int* __restrict__ tabp,
    const unsigned int* __restrict__ yzp,
    const unsigned short* __restrict__ o1f, const float* __restrict__ o1b,
    const unsigned short* __restrict__ o2f, const float* __restrict__ o2b,
    const float* __restrict__ embed,
    float* __restrict__ out, int N, int ngroups)
{
    extern __shared__ unsigned int smem[];
    unsigned int*   tabL = smem;                                   // 11328 u32
    unsigned int*   aggL = smem + 11328;                           // 1024 u32
    unsigned short* Us   = (unsigned short*)(smem + 11328 + 1024); // 2048 u16

    int tid  = threadIdx.x;
    int wid  = tid >> 6;
    int lane = tid & 63;
    int lr   = lane & 15;
    int lg   = lane >> 4;

    for (int m = tid; m < (TN + 1) * 64; m += 512)
        tabL[m] = tabp[m];
    __syncthreads();

    for (int g = blockIdx.x; g < ngroups; g += gridDim.x) {
        int n0 = g * 16;

        // ---------- phase 1: pair aggregation, 2 atoms per wave ----------
        int aA = wid * 2, aB = aA + 1;
        int nA = n0 + aA, nB = n0 + aB;
        float a0 = 0.f, a1 = 0.f, b0 = 0.f, b1 = 0.f;
        if (nA < N) {
            int mB = (nB < N) ? nB : nA;

            // --- on-the-fly params: lane k holds atom's k-th pair ---
            unsigned int pA = 0, pB = 0;
            if (lane < KN) {
                float dA = dR[nA * KN + lane];
                int   iA = nbr[nA * KN + lane];
                float uA = dA * ((float)TN / 5.0f);
                int   jA = (int)uA; jA = (jA > TN - 1) ? (TN - 1) : jA;
                float fA = uA - (float)jA;
                unsigned int zA = (iA >= 0 && iA < N) ? (unsigned int)Z[iA] : (unsigned int)MAXZ;
                pA = ((unsigned int)f2h(fA) << 16) | ((unsigned int)jA << 7) | zA;

                float dB = dR[mB * KN + lane];
                int   iB = nbr[mB * KN + lane];
                float uB = dB * ((float)TN / 5.0f);
                int   jB = (int)uB; jB = (jB > TN - 1) ? (TN - 1) : jB;
                float fB = uB - (float)jB;
                unsigned int zB = (iB >= 0 && iB < N) ? (unsigned int)Z[iB] : (unsigned int)MAXZ;
                pB = ((unsigned int)f2h(fB) << 16) | ((unsigned int)jB << 7) | zB;
            }

            #pragma unroll
            for (int c = 0; c < 4; ++c) {
                __half2 pacA = u2h2(0u);
                __half2 pacB = u2h2(0u);
                #pragma unroll
                for (int k2 = 0; k2 < 12; ++k2) {
                    int k = c * 12 + k2;
                    unsigned int qA = (unsigned int)__builtin_amdgcn_readlane((int)pA, k);
                    unsigned int qB = (unsigned int)__builtin_amdgcn_readlane((int)pB, k);

                    __half2 frA = u2h2((qA & 0xFFFF0000u) | (qA >> 16));
                    __half2 frB = u2h2((qB & 0xFFFF0000u) | (qB >> 16));
                    unsigned int jbA = (qA & 0x7F80u) << 1;   // j*256 bytes
                    unsigned int jbB = (qB & 0x7F80u) << 1;
                    unsigned int zbA = (qA & 0x7Fu) << 8;     // z*256 bytes
                    unsigned int zbB = (qB & 0x7Fu) << 8;

                    const unsigned int* rA = (const unsigned int*)((const char*)tabL + jbA);
                    const unsigned int* rB = (const unsigned int*)((const char*)tabL + jbB);
                    __half2 tA0 = u2h2(rA[lane]);
                    __half2 tA1 = u2h2(rA[lane + 64]);
                    __half2 tB0 = u2h2(rB[lane]);
                    __half2 tB1 = u2h2(rB[lane + 64]);
                    __half2 yA  = u2h2(*(const unsigned int*)((const char*)yzp + zbA + (lane << 2)));
                    __half2 yB  = u2h2(*(const unsigned int*)((const char*)yzp + zbB + (lane << 2)));

                    __half2 wA = __hfma2(frA, __hsub2(tA1, tA0), tA0);
                    __half2 wB = __hfma2(frB, __hsub2(tB1, tB0), tB0);
                    pacA = __hfma2(wA, yA, pacA);
                    pacB = __hfma2(wB, yB, pacB);
                }
                float2 fa = __half22float2(pacA); a0 += fa.x; a1 += fa.y;
                float2 fb = __half22float2(pacB); b0 += fb.x; b1 += fb.y;
            }
        }
        // swizzled store: word idx = a*64 + (lane ^ (a<<2))
        aggL[aA * 64 + (lane ^ (aA << 2))] = (unsigned int)f2h(a0) | ((unsigned int)f2h(a1) << 16);
        aggL[aB * 64 + (lane ^ (aB << 2))] = (unsigned int)f2h(b0) | ((unsigned int)f2h(b1) << 16);
        __syncthreads();                       // bar1: aggL ready

        // ---------- phase 2: output network (f16 MFMA), col-tile = wid ----------
        f32x4 c1 = {0.f, 0.f, 0.f, 0.f};
        #pragma unroll
        for (int kt = 0; kt < 4; ++kt) {
            f16x8 b = *reinterpret_cast<const f16x8*>(o1f + (((kt * 8 + wid) * 64 + lane) << 3));
            const char* ap = (const char*)aggL + lr * 256 + ((kt * 64 + lg * 16) ^ (lr << 4));
            f16x8 a = *reinterpret_cast<const f16x8*>(ap);
            c1 = __builtin_amdgcn_mfma_f32_16x16x32_f16(a, b, c1, 0, 0, 0);
        }
        int fcol = wid * 16 + lr;
        float bv1 = o1b[fcol];
        #pragma unroll
        for (int jr = 0; jr < 4; ++jr) {
            int r = lg * 4 + jr;
            float u = ssp(c1[jr] + bv1);
            Us[r * F + (fcol ^ (r << 3))] = f2h(u);
        }
        __syncthreads();                       // bar2: Us ready

        f32x4 c2 = {0.f, 0.f, 0.f, 0.f};
        #pragma unroll
        for (int kt = 0; kt < 4; ++kt) {
            f16x8 b = *reinterpret_cast<const f16x8*>(o2f + (((kt * 8 + wid) * 64 + lane) << 3));
            f16x8 a = *reinterpret_cast<const f16x8*>(&Us[lr * F + ((kt * 32 + lg * 8) ^ (lr << 3))]);
            c2 = __builtin_amdgcn_mfma_f32_16x16x32_f16(a, b, c2, 0, 0, 0);
        }
        float bv2 = o2b[fcol];
        #pragma unroll
        for (int jr = 0; jr < 4; ++jr) {
            int r = lg * 4 + jr;
            int n = n0 + r;
            if (n < N) {
                float x = embed[Z[n] * F + fcol];
                out[n * F + fcol] = x + c2[jr] + bv2;
            }
        }
    }
}

extern "C" void kernel_launch(void* const* d_in, const int* in_sizes, int n_in,
                              void* d_out, int out_size, void* d_ws, size_t ws_size,
                              hipStream_t stream) {
    const float* dR    = (const float*)d_in[0];
    const int*   Z     = (const int*)  d_in[1];
    const int*   nbr   = (const int*)  d_in[2];
    const float* embed = (const float*)d_in[3];
    const float* in2f  = (const float*)d_in[4];
    const float* f1w   = (const float*)d_in[5];
    const float* f1b   = (const float*)d_in[6];
    const float* f2w   = (const float*)d_in[7];
    const float* f2b   = (const float*)d_in[8];
    const float* o1w   = (const float*)d_in[9];
    const float* o1b   = (const float*)d_in[10];
    const float* o2w   = (const float*)d_in[11];
    const float* o2b   = (const float*)d_in[12];

    int N = in_sizes[1];

    // ws layout (16B-aligned), ~135 KB total
    char* wp = (char*)d_ws;
    unsigned int*   tabp = (unsigned int*)wp;   wp += (size_t)(TN + 1) * 64 * 4;   // 45.3 KB
    unsigned int*   yzp  = (unsigned int*)wp;   wp += (size_t)(MAXZ + 1) * 64 * 4; // 25.9 KB
    unsigned short* o1f  = (unsigned short*)wp; wp += 16384 * 2;                   // 32 KB
    unsigned short* o2f  = (unsigned short*)wp;                                    // 32 KB

    int grid_prep = (TN + 1) + 128 + (MAXZ + 1);

    int ngroups   = (N + 15) / 16;
    int grid_main = (ngroups < 768) ? ngroups : 768;
    int lds_main  = (TN + 1) * 64 * 4 + 4096 + 4096;   // 53504 B -> 3 blocks/CU

    (void)hipFuncSetAttribute((const void*)k_main,
                              hipFuncAttributeMaxDynamicSharedMemorySize, lds_main);

    k_prep<<<grid_prep, 256, 0, stream>>>(f1w, f1b, f2w, f2b, o1w, o2w,
                                          embed, in2f, tabp, yzp, o1f, o2f, N);
    k_main<<<grid_main, 512, lds_main, stream>>>(dR, nbr, Z, tabp, yzp,
                                                 o1f, o1b, o2f, o2b,
                                                 embed, (float*)d_out,
                                                 N, ngroups);
}